// Round 12
// baseline (418.756 us; speedup 1.0000x reference)
//
#include <hip/hip_runtime.h>

#define NPTS 1048576
#define NBKT 262144  // 2^18 Morton buckets

typedef short bhalf8 __attribute__((ext_vector_type(8)));
typedef _Float16 halfv8 __attribute__((ext_vector_type(8)));
typedef _Float16 halfv2 __attribute__((ext_vector_type(2)));
typedef float floatx4 __attribute__((ext_vector_type(4)));

#define WSZ 24320  // f16 elements of weight storage
#define MLP_THREADS 1024
#define MLP_WAVES 16

// prep_kernel block ranges
#define PB_PLANES 16320  // 4177920 texels / 256
#define PB_HASH 4096
#define PB_HIST 4096

__device__ const float HRg[16] = {16.f, 19.f, 24.f, 30.f, 37.f, 46.f, 57.f, 71.f,
                                  89.f, 110.f, 136.f, 169.f, 210.f, 260.f, 322.f, 400.f};

// ---------------- helpers ----------------

__device__ __forceinline__ float my_tanh(float x) {
  float e = __expf(2.f * x);
  return 1.f - 2.f * __builtin_amdgcn_rcpf(e + 1.f);
}

__device__ __forceinline__ float my_sigmoid(float x) {
  return __builtin_amdgcn_rcpf(1.f + __expf(-x));
}

__device__ __forceinline__ unsigned short f2h(float v) {
  _Float16 h = (_Float16)v;
  unsigned short u;
  __builtin_memcpy(&u, &h, 2);
  return u;
}

__device__ __forceinline__ float h2f(unsigned short u) {
  _Float16 h;
  __builtin_memcpy(&h, &u, 2);
  return (float)h;
}

__device__ __forceinline__ float texch(uint2 t, int c) {
  unsigned short u = (c == 0) ? (unsigned short)(t.x & 0xffffu)
                   : (c == 1) ? (unsigned short)(t.x >> 16)
                              : (unsigned short)(t.y & 0xffffu);
  return h2f(u);
}

__device__ __forceinline__ unsigned mort6(unsigned x) {
  return (x & 1) | ((x & 2) << 2) | ((x & 4) << 4) |
         ((x & 8) << 6) | ((x & 16) << 8) | ((x & 32) << 10);
}

__device__ __forceinline__ unsigned morton_key(float px, float py, float pz) {
  float qx = (px + 4.f) * 0.125f, qy = (py + 4.f) * 0.125f, qz = (pz + 2.f) * 0.25f;
  unsigned kx = min(63, max(0, (int)(qx * 64.f)));
  unsigned ky = min(63, max(0, (int)(qy * 64.f)));
  unsigned kz = min(63, max(0, (int)(qz * 64.f)));
  return mort6(kx) | (mort6(ky) << 1) | (mort6(kz) << 2);
}

// one hash level -> packed 2xf16 pair (packed f16 interpolation)
__device__ __forceinline__ unsigned hash_level(const unsigned* __restrict__ ht, int lv,
                                               float q0, float q1, float q2) {
  const float r = HRg[lv];
  float x0 = q0 * r, x1 = q1 * r, x2 = q2 * r;
  float f0 = floorf(x0), f1 = floorf(x1), f2 = floorf(x2);
  float w0 = x0 - f0, w1 = x1 - f1, w2 = x2 - f2;
  unsigned i0 = (unsigned)(int)f0, i1 = (unsigned)(int)f1, i2 = (unsigned)(int)f2;
  const unsigned* __restrict__ hb = ht + ((unsigned)lv << 16);
  unsigned tv[8];
#pragma unroll
  for (int dz = 0; dz < 2; ++dz)
#pragma unroll
    for (int dy = 0; dy < 2; ++dy)
#pragma unroll
      for (int dx = 0; dx < 2; ++dx) {
        unsigned h = (i0 + dx) ^ ((i1 + dy) * 2654435761u) ^ ((i2 + dz) * 805459861u);
        tv[dz * 4 + dy * 2 + dx] = hb[h & 65535u];
      }
  halfv2 acc2 = {(_Float16)0.f, (_Float16)0.f};
#pragma unroll
  for (int c = 0; c < 8; ++c) {
    const int dx = c & 1, dy = (c >> 1) & 1, dz = c >> 2;
    float wgt = (dx ? w0 : 1.f - w0) * (dy ? w1 : 1.f - w1) * (dz ? w2 : 1.f - w2);
    halfv2 th;
    __builtin_memcpy(&th, &tv[c], 4);
    _Float16 wh = (_Float16)wgt;
    halfv2 w2v = {wh, wh};
    acc2 = th * w2v + acc2;
  }
  unsigned res;
  __builtin_memcpy(&res, &acc2, 4);
  return res;
}

// one plane sample (s in 0..11) -> 4 padded f16 channels as uint2 {c0|c1, c2|0}
__device__ __forceinline__ uint2 sampleP(const uint2* __restrict__ planes, int s,
                                         float u, float v, float w) {
  const int level = s / 3;
  const int m = s - level * 3;
  const float a = (m == 2) ? v : u;
  const float b = (m == 0) ? v : w;
  const int R = 128 << level;
  const unsigned base = 16384u * ((1u << (2 * level)) - 1u) + (unsigned)m * (unsigned)(R * R);
  const float Rm1 = (float)(R - 1);
  float x = fminf(fmaxf((a + 1.f) * 0.5f * Rm1, 0.f), Rm1);
  float y = fminf(fmaxf((b + 1.f) * 0.5f * Rm1, 0.f), Rm1);
  float x0f = floorf(x), y0f = floorf(y);
  float wx = x - x0f, wy = y - y0f;
  int x0 = (int)x0f, y0 = (int)y0f;
  int x1 = min(x0 + 1, R - 1), y1 = min(y0 + 1, R - 1);
  uint2 t00 = planes[base + y0 * R + x0];
  uint2 t01 = planes[base + y0 * R + x1];
  uint2 t10 = planes[base + y1 * R + x0];
  uint2 t11 = planes[base + y1 * R + x1];
  _Float16 h00 = (_Float16)((1.f - wy) * (1.f - wx));
  _Float16 h01 = (_Float16)((1.f - wy) * wx);
  _Float16 h10 = (_Float16)(wy * (1.f - wx));
  _Float16 h11 = (_Float16)(wy * wx);
  halfv2 w00 = {h00, h00}, w01 = {h01, h01}, w10 = {h10, h10}, w11 = {h11, h11};
  halfv2 l00, l01, l10, l11, u00, u01, u10, u11;
  __builtin_memcpy(&l00, &t00.x, 4); __builtin_memcpy(&u00, &t00.y, 4);
  __builtin_memcpy(&l01, &t01.x, 4); __builtin_memcpy(&u01, &t01.y, 4);
  __builtin_memcpy(&l10, &t10.x, 4); __builtin_memcpy(&u10, &t10.y, 4);
  __builtin_memcpy(&l11, &t11.x, 4); __builtin_memcpy(&u11, &t11.y, 4);
  halfv2 alo = l00 * w00 + l01 * w01 + l10 * w10 + l11 * w11;
  halfv2 ahi = u00 * w00 + u01 * w01 + u10 * w10 + u11 * w11;
  uint2 r;
  __builtin_memcpy(&r.x, &alo, 4);
  __builtin_memcpy(&r.y, &ahi, 4);
  return r;
}

// ---------------- fused prep kernel ----------------

struct PrepParams {
  const float* psrc[12];
  ushort4* pdst[12];
  const float* hash;
  unsigned* hashb;
  const float* p;
  unsigned* hist;
};

__global__ __launch_bounds__(256) void prep_kernel(PrepParams P) {
  const int b = blockIdx.x;
  if (b < PB_PLANES) {
    const int CUM[13] = {0, 16384, 32768, 49152, 114688, 180224, 245760,
                         507904, 770048, 1032192, 2080768, 3129344, 4177920};
    const int RESL[12] = {128, 128, 128, 256, 256, 256, 512, 512, 512, 1024, 1024, 1024};
    const int s = b << 8;
    int pi = 0;
#pragma unroll
    for (int i = 1; i < 12; ++i)
      if (s >= CUM[i]) pi = i;
    const int li = s + threadIdx.x - CUM[pi];
    const int R = RESL[pi];
    const int n = R * R;
    const float* __restrict__ src = P.psrc[pi];
    ushort4 t;
    t.x = f2h(src[li]);
    t.y = f2h(src[n + li]);
    t.z = f2h(src[2 * n + li]);
    t.w = 0;
    P.pdst[pi][li] = t;
  } else if (b < PB_PLANES + PB_HASH) {
    const int i = ((b - PB_PLANES) << 8) + threadIdx.x;
    float2 v = *(const float2*)(P.hash + (size_t)i * 2);
    P.hashb[i] = (unsigned)f2h(v.x) | ((unsigned)f2h(v.y) << 16);
  } else {
    const int i = ((b - PB_PLANES - PB_HASH) << 8) + threadIdx.x;
    const float* pp = P.p + (size_t)i * 3;
    unsigned k = morton_key(pp[0], pp[1], pp[2]);
    atomicAdd(&P.hist[k], 1u);
  }
}

// ---------------- hierarchical scan ----------------

__global__ __launch_bounds__(256) void scan1_kernel(const unsigned* __restrict__ hist,
                                                    unsigned* __restrict__ partial) {
  __shared__ unsigned s[256];
  const int b = blockIdx.x, t = threadIdx.x;
  uint4 v = ((const uint4*)(hist + b * 1024))[t];
  s[t] = v.x + v.y + v.z + v.w;
  __syncthreads();
  for (int d = 128; d > 0; d >>= 1) {
    if (t < d) s[t] += s[t + d];
    __syncthreads();
  }
  if (t == 0) partial[b] = s[0];
}

__global__ __launch_bounds__(256) void scan2_kernel(const unsigned* __restrict__ partial,
                                                    unsigned* __restrict__ base) {
  __shared__ unsigned s[256];
  const int t = threadIdx.x;
  s[t] = partial[t];
  __syncthreads();
  for (int d = 1; d < 256; d <<= 1) {
    unsigned v = (t >= d) ? s[t - d] : 0u;
    __syncthreads();
    s[t] += v;
    __syncthreads();
  }
  base[t] = (t == 0) ? 0u : s[t - 1];
}

__global__ __launch_bounds__(256) void scan3_kernel(const unsigned* __restrict__ hist,
                                                    const unsigned* __restrict__ base,
                                                    unsigned* __restrict__ cursor) {
  __shared__ unsigned s[256];
  const int b = blockIdx.x, t = threadIdx.x;
  uint4 v = ((const uint4*)(hist + b * 1024))[t];
  unsigned sum = v.x + v.y + v.z + v.w;
  s[t] = sum;
  __syncthreads();
  for (int d = 1; d < 256; d <<= 1) {
    unsigned x = (t >= d) ? s[t - d] : 0u;
    __syncthreads();
    s[t] += x;
    __syncthreads();
  }
  unsigned off = base[b] + s[t] - sum;
  uint4 c;
  c.x = off;
  c.y = off + v.x;
  c.z = off + v.x + v.y;
  c.w = off + v.x + v.y + v.z;
  ((uint4*)(cursor + b * 1024))[t] = c;
}

// scatter: write sorted {q0,q1,q2,pid} per slot
__global__ __launch_bounds__(256) void scatter_kernel(const float* __restrict__ p,
                                                      unsigned* __restrict__ cursor,
                                                      float4* __restrict__ qs) {
  int i = blockIdx.x * 256 + threadIdx.x;
  const float* pp = p + (size_t)i * 3;
  const float px = pp[0], py = pp[1], pz = pp[2];
  unsigned k = morton_key(px, py, pz);
  unsigned slot = atomicAdd(&cursor[k], 1u);
  float4 q;
  q.x = (px + 4.f) * 0.125f;
  q.y = (py + 4.f) * 0.125f;
  q.z = (pz + 2.f) * 0.25f;
  q.w = __uint_as_float((unsigned)i);
  qs[slot] = q;
}

// ---------------- repack kernel (fallback only) ----------------

__global__ __launch_bounds__(256) void repack_plane(const float* __restrict__ src,
                                                    ushort4* __restrict__ dst, int R) {
  int i = blockIdx.x * 256 + threadIdx.x;
  int n = R * R;
  if (i >= n) return;
  ushort4 t;
  t.x = f2h(src[i]);
  t.y = f2h(src[n + i]);
  t.z = f2h(src[2 * n + i]);
  t.w = 0;
  dst[i] = t;
}

// ---------------- plane samplers (fallback) ----------------

__device__ __forceinline__ void sample3i(const uint2* __restrict__ pl,
                                         float a, float b, int R, float* f) {
  const float Rm1 = (float)(R - 1);
  float x = fminf(fmaxf((a + 1.f) * 0.5f * Rm1, 0.f), Rm1);
  float y = fminf(fmaxf((b + 1.f) * 0.5f * Rm1, 0.f), Rm1);
  float x0f = floorf(x), y0f = floorf(y);
  float wx = x - x0f, wy = y - y0f;
  int x0 = (int)x0f, y0 = (int)y0f;
  int x1 = min(x0 + 1, R - 1), y1 = min(y0 + 1, R - 1);
  float w00 = (1.f - wy) * (1.f - wx);
  float w01 = (1.f - wy) * wx;
  float w10 = wy * (1.f - wx);
  float w11 = wy * wx;
  uint2 t00 = pl[y0 * R + x0];
  uint2 t01 = pl[y0 * R + x1];
  uint2 t10 = pl[y1 * R + x0];
  uint2 t11 = pl[y1 * R + x1];
#pragma unroll
  for (int c = 0; c < 3; ++c) {
    f[c] = texch(t00, c) * w00 + texch(t01, c) * w01 +
           texch(t10, c) * w10 + texch(t11, c) * w11;
  }
}

__device__ __forceinline__ void sample3f(const float* __restrict__ pl,
                                         float a, float b, int R, float* f) {
  const float Rm1 = (float)(R - 1);
  float x = fminf(fmaxf((a + 1.f) * 0.5f * Rm1, 0.f), Rm1);
  float y = fminf(fmaxf((b + 1.f) * 0.5f * Rm1, 0.f), Rm1);
  float x0f = floorf(x), y0f = floorf(y);
  float wx = x - x0f, wy = y - y0f;
  int x0 = (int)x0f, y0 = (int)y0f;
  int x1 = min(x0 + 1, R - 1), y1 = min(y0 + 1, R - 1);
  float w00 = (1.f - wy) * (1.f - wx);
  float w01 = (1.f - wy) * wx;
  float w10 = wy * (1.f - wx);
  float w11 = wy * wx;
  int i00 = y0 * R + x0, i01 = y0 * R + x1;
  int i10 = y1 * R + x0, i11 = y1 * R + x1;
  const int R2 = R * R;
#pragma unroll
  for (int c = 0; c < 3; ++c) {
    const float* base = pl + c * R2;
    f[c] = base[i00] * w00 + base[i01] * w01 + base[i10] * w10 + base[i11] * w11;
  }
}

// ---------------- fused MFMA kernel (planes + hash + MLP) ----------------
// Feature padding: planes 12 samples x 4 ch (ch3=0) = k 0..47; hash 16 lv x 2 = k 48..79; pad to 96.
// B-frag lane (pt=rowl, grp): slice0 = samples {2g,2g+1}; slice1 = g<2 ? samples {8+2g,9+2g} : hash lv {4(g-2)..+3};
// slice2 = g<2 ? hash lv {8+4g..+3} : zero.
// Lc0: k 0..31 geo; k 32..79 = pf padded; slice1 = L0 slice0 frag; slice2 = g<2 ? L0 slice1 frag : zero.

struct MlpWParams {
  const uint2* planes;
  const unsigned* hashb;
  const float4* qs;
  const float* W0; const float* b0;
  const float* W1; const float* b1;
  const float* Wo; const float* bo;
  const float* Wc0; const float* bc0;
  const float* Wc1; const float* bc1;
  const float* Wco; const float* bco;
  float* out;
};

// MODE 0: W0 (planes padded + hash); MODE 1: Wc0 (geo + planes padded); MODE 2: direct
template <int MODE>
__device__ __forceinline__ void stage_w(const float* __restrict__ src, int K, int Nsrc,
                                        int STR, int NPAD, int OFF, short* Wlds, int tid) {
  const int total = NPAD * STR;
  for (int idx = tid; idx < total; idx += MLP_THREADS) {
    int c = idx / STR;
    int kp = idx - c * STR;
    int sk = -1;
    if (MODE == 0) {
      if (kp < 48) {
        int s = kp >> 2, ch = kp & 3;
        if (ch < 3) sk = s * 3 + ch;
      } else if (kp < 80) {
        sk = 36 + (kp - 48);
      }
    } else if (MODE == 1) {
      if (kp < 32) {
        sk = kp;
      } else if (kp < 80) {
        int s = (kp - 32) >> 2, ch = (kp - 32) & 3;
        if (ch < 3) sk = 32 + s * 3 + ch;
      }
    } else {
      if (kp < K) sk = kp;
    }
    float val = (sk >= 0 && c < Nsrc) ? src[sk * Nsrc + c] : 0.f;
    Wlds[OFF + idx] = (short)f2h(val);
  }
}

__device__ __forceinline__ void stage_b(const float* __restrict__ src, int Nsrc, int NPAD,
                                        int BOFF, float* Blds, int tid) {
  for (int j = tid; j < NPAD; j += MLP_THREADS) Blds[BOFF + j] = (j < Nsrc) ? src[j] : 0.f;
}

__device__ __forceinline__ halfv8 as_h8(bhalf8 s) {
  halfv8 h;
  __builtin_memcpy(&h, &s, 16);
  return h;
}

__device__ __forceinline__ halfv8 frag4(unsigned d0, unsigned d1, unsigned d2, unsigned d3) {
  bhalf8 r;
  r[0] = (short)(d0 & 0xffffu); r[1] = (short)(d0 >> 16);
  r[2] = (short)(d1 & 0xffffu); r[3] = (short)(d1 >> 16);
  r[4] = (short)(d2 & 0xffffu); r[5] = (short)(d2 >> 16);
  r[6] = (short)(d3 & 0xffffu); r[7] = (short)(d3 >> 16);
  return as_h8(r);
}

__device__ __forceinline__ halfv8 ldS(const short* scr, int rowl, int grp, int s) {
  return *(const halfv8*)&scr[rowl * 72 + 32 * s + 8 * grp];
}

template <int NT, int KS, int OFF, int STR>
__device__ __forceinline__ void mlayer(const halfv8 (&af)[KS], floatx4 (&acc)[NT],
                                       const short* Wlds, int rowl, int grp) {
#pragma unroll
  for (int n = 0; n < NT; ++n) {
    floatx4 a{};
#pragma unroll
    for (int s = 0; s < KS; ++s) {
      const int wo = OFF + (16 * n + rowl) * STR + 32 * s + 8 * grp;
      const halfv8 wA = *(const halfv8*)&Wlds[wo];
      a = __builtin_amdgcn_mfma_f32_16x16x32_f16(wA, af[s], a, 0, 0, 0);
    }
    acc[n] = a;
  }
}

template <int NT>
__device__ __forceinline__ void relu_wr(const floatx4 (&acc)[NT], const float* Blds,
                                        int boff, short* scr, int rowl, int grp) {
#pragma unroll
  for (int n = 0; n < NT; ++n) {
    const int cbase = 16 * n + 4 * grp;
    short4 v4;
    float v0 = fmaxf(acc[n][0] + Blds[boff + cbase + 0], 0.f);
    float v1 = fmaxf(acc[n][1] + Blds[boff + cbase + 1], 0.f);
    float v2 = fmaxf(acc[n][2] + Blds[boff + cbase + 2], 0.f);
    float v3 = fmaxf(acc[n][3] + Blds[boff + cbase + 3], 0.f);
    v4.x = (short)f2h(v0);
    v4.y = (short)f2h(v1);
    v4.z = (short)f2h(v2);
    v4.w = (short)f2h(v3);
    *(short4*)&scr[rowl * 72 + cbase] = v4;
  }
}

__device__ __forceinline__ void tanh_wr(const floatx4 (&acc)[3], const float* Blds,
                                        short* scr, float* ost, int rowl, int grp) {
#pragma unroll
  for (int n = 0; n < 3; ++n) {
#pragma unroll
    for (int r = 0; r < 4; ++r) {
      const int c = 16 * n + 4 * grp + r;
      float v = my_tanh(acc[n][r] + Blds[128 + c]);
      if (c == 0) ost[rowl * 4 + 3] = v;
      if (c >= 1 && c <= 32) scr[rowl * 72 + c - 1] = (short)f2h(v);
    }
  }
}

__global__ __launch_bounds__(MLP_THREADS) void mlp_fused(MlpWParams P) {
  __shared__ short Wlds[WSZ];                      // 48,640 B
  __shared__ float Blds[288];                      //  1,152 B
  __shared__ short Scr[MLP_WAVES * 16 * 72];       // 36,864 B
  __shared__ float Ost[MLP_WAVES][16][4];          //  4,096 B

  const int tid = threadIdx.x;

  stage_w<0>(P.W0,  96, 64, 104, 64,     0, Wlds, tid);
  stage_w<2>(P.W1,  64, 64,  72, 64,  6656, Wlds, tid);
  stage_w<2>(P.Wo,  64, 33,  72, 48, 11264, Wlds, tid);
  stage_w<1>(P.Wc0, 96, 64, 104, 64, 14720, Wlds, tid);
  stage_w<2>(P.Wc1, 64, 32,  72, 32, 21376, Wlds, tid);
  stage_w<2>(P.Wco, 32,  3,  40, 16, 23680, Wlds, tid);
  stage_b(P.b0,  64, 64,   0, Blds, tid);
  stage_b(P.b1,  64, 64,  64, Blds, tid);
  stage_b(P.bo,  33, 48, 128, Blds, tid);
  stage_b(P.bc0, 64, 64, 176, Blds, tid);
  stage_b(P.bc1, 32, 32, 240, Blds, tid);
  stage_b(P.bco,  3, 16, 272, Blds, tid);
  __syncthreads();

  const int wave = tid >> 6, lane = tid & 63;
  const int rowl = lane & 15, grp = lane >> 4;
  short* scr0 = &Scr[wave * 16 * 72];
  float* ost0 = &Ost[wave][0][0];

  // XCD-chunked block mapping (512 blocks, 64 per XCD chunk)
  int bid = blockIdx.x;
  bid = (bid & 7) * 64 + (bid >> 3);

  for (int t = 0; t < 8; ++t) {
    const int wbase = ((bid * 8 + t) * MLP_WAVES + wave) * 16;
    const int pt = wbase + rowl;

    float4 q4 = P.qs[pt];
    const float q0 = q4.x, q1 = q4.y, q2 = q4.z;
    const unsigned pid = __float_as_uint(q4.w);
    const float u = 2.f * q0 - 1.f;
    const float v = 2.f * q1 - 1.f;
    const float w = 2.f * q2 - 1.f;

    // ---- gather phase: plane samples + hash levels (all independent loads) ----
    uint2 sA = sampleP(P.planes, 2 * grp, u, v, w);
    uint2 sB = sampleP(P.planes, 2 * grp + 1, u, v, w);
    uint2 sC = {0u, 0u}, sD = {0u, 0u};
    if (grp < 2) {
      sC = sampleP(P.planes, 8 + 2 * grp, u, v, w);
      sD = sampleP(P.planes, 9 + 2 * grp, u, v, w);
    }
    const int lbase = (grp < 2) ? (8 + 4 * grp) : (4 * grp - 8);
    unsigned h0 = hash_level(P.hashb, lbase + 0, q0, q1, q2);
    unsigned h1 = hash_level(P.hashb, lbase + 1, q0, q1, q2);
    unsigned h2 = hash_level(P.hashb, lbase + 2, q0, q1, q2);
    unsigned h3 = hash_level(P.hashb, lbase + 3, q0, q1, q2);

    halfv8 af0 = frag4(sA.x, sA.y, sB.x, sB.y);
    halfv8 af1 = (grp < 2) ? frag4(sC.x, sC.y, sD.x, sD.y) : frag4(h0, h1, h2, h3);
    halfv8 af2 = (grp < 2) ? frag4(h0, h1, h2, h3) : frag4(0u, 0u, 0u, 0u);
    halfv8 zf = frag4(0u, 0u, 0u, 0u);

    // ---- L0 ----
    {
      halfv8 afA[3] = {af0, af1, af2};
      floatx4 accA[4];
      mlayer<4, 3, 0, 104>(afA, accA, Wlds, rowl, grp);
      relu_wr<4>(accA, Blds, 0, scr0, rowl, grp);
    }
    // ---- L1 ----
    {
      halfv8 afA[2] = {ldS(scr0, rowl, grp, 0), ldS(scr0, rowl, grp, 1)};
      floatx4 accA[4];
      mlayer<4, 2, 6656, 72>(afA, accA, Wlds, rowl, grp);
      relu_wr<4>(accA, Blds, 64, scr0, rowl, grp);
    }
    // ---- Lo ----
    {
      halfv8 afA[2] = {ldS(scr0, rowl, grp, 0), ldS(scr0, rowl, grp, 1)};
      floatx4 accA[3];
      mlayer<3, 2, 11264, 72>(afA, accA, Wlds, rowl, grp);
      tanh_wr(accA, Blds, scr0, ost0, rowl, grp);
    }
    // ---- Lc0 (reuse L0 fragments) ----
    {
      halfv8 afA[3] = {ldS(scr0, rowl, grp, 0), af0, (grp < 2) ? af1 : zf};
      floatx4 accA[4];
      mlayer<4, 3, 14720, 104>(afA, accA, Wlds, rowl, grp);
      relu_wr<4>(accA, Blds, 176, scr0, rowl, grp);
    }
    // ---- Lc1 ----
    {
      halfv8 afA[2] = {ldS(scr0, rowl, grp, 0), ldS(scr0, rowl, grp, 1)};
      floatx4 accA[2];
      mlayer<2, 2, 21376, 72>(afA, accA, Wlds, rowl, grp);
      relu_wr<2>(accA, Blds, 240, scr0, rowl, grp);
    }
    // ---- Lco ----
    {
      halfv8 afA[1] = {ldS(scr0, rowl, grp, 0)};
      floatx4 accA[1];
      mlayer<1, 1, 23680, 40>(afA, accA, Wlds, rowl, grp);
#pragma unroll
      for (int r = 0; r < 4; ++r) {
        const int c = 4 * grp + r;
        if (c < 3) {
          float vA = my_sigmoid(accA[0][r] + Blds[272 + c]);
          ost0[rowl * 4 + c] = vA;
        }
      }
    }

    // ---- store 16 points (lane<16 => rowl==lane, grp==0, own pid valid) ----
    if (lane < 16) {
      float4 o = *(float4*)&Ost[wave][lane][0];
      ((float4*)P.out)[pid] = o;
    }
  }
}

// ---------------- fused fallback (Round-2 style kernel) ----------------

struct DecParams {
  const float* p;
  const float* pl[12];
  const uint2* pli[12];
  const float* hash;
  const float* W0; const float* b0;
  const float* W1; const float* b1;
  const float* Wo; const float* bo;
  const float* Wc0; const float* bc0;
  const float* Wc1; const float* bc1;
  const float* Wco; const float* bco;
  float* out;
};

template <bool ILV>
__global__ __launch_bounds__(256) void dec_kernel(DecParams P) {
  const int tid = blockIdx.x * 256 + threadIdx.x;

  const float* __restrict__ pp = P.p + (size_t)tid * 3;
  const float px = pp[0], py = pp[1], pz = pp[2];

  const float u = (px + 4.f) * 0.25f - 1.f;
  const float v = (py + 4.f) * 0.25f - 1.f;
  const float w = (pz + 2.f) * 0.5f - 1.f;

  float feat[68];
  {
    const int RES[4] = {128, 256, 512, 1024};
#pragma unroll
    for (int li = 0; li < 4; ++li) {
      if (ILV) {
        sample3i(P.pli[li * 3 + 0], u, v, RES[li], &feat[li * 9 + 0]);
        sample3i(P.pli[li * 3 + 1], u, w, RES[li], &feat[li * 9 + 3]);
        sample3i(P.pli[li * 3 + 2], v, w, RES[li], &feat[li * 9 + 6]);
      } else {
        sample3f(P.pl[li * 3 + 0], u, v, RES[li], &feat[li * 9 + 0]);
        sample3f(P.pl[li * 3 + 1], u, w, RES[li], &feat[li * 9 + 3]);
        sample3f(P.pl[li * 3 + 2], v, w, RES[li], &feat[li * 9 + 6]);
      }
    }
  }

  {
    const float q0 = (px + 4.f) * 0.125f;
    const float q1 = (py + 4.f) * 0.125f;
    const float q2 = (pz + 2.f) * 0.25f;
    const float* __restrict__ ht = P.hash;
#pragma unroll
    for (int l = 0; l < 16; ++l) {
      const float r = HRg[l];
      float x0 = q0 * r, x1 = q1 * r, x2 = q2 * r;
      float f0 = floorf(x0), f1 = floorf(x1), f2 = floorf(x2);
      float w0 = x0 - f0, w1 = x1 - f1, w2 = x2 - f2;
      unsigned i0 = (unsigned)(int)f0, i1 = (unsigned)(int)f1, i2 = (unsigned)(int)f2;
      float a0 = 0.f, a1 = 0.f;
#pragma unroll
      for (int dz = 0; dz < 2; ++dz)
#pragma unroll
        for (int dy = 0; dy < 2; ++dy)
#pragma unroll
          for (int dx = 0; dx < 2; ++dx) {
            unsigned h = (i0 + dx) ^ ((i1 + dy) * 2654435761u) ^ ((i2 + dz) * 805459861u);
            unsigned idx = h & 65535u;
            const float2 tv = *(const float2*)(ht + (((unsigned)l << 16) + idx) * 2);
            float wgt = (dx ? w0 : 1.f - w0) * (dy ? w1 : 1.f - w1) * (dz ? w2 : 1.f - w2);
            a0 = fmaf(tv.x, wgt, a0);
            a1 = fmaf(tv.y, wgt, a1);
          }
      feat[36 + l * 2] = a0;
      feat[36 + l * 2 + 1] = a1;
    }
  }

  float acc[64];
#pragma unroll
  for (int j = 0; j < 64; ++j) acc[j] = P.b0[j];
#pragma unroll
  for (int i = 0; i < 68; ++i) {
    const float a = feat[i];
    const float* wr = P.W0 + i * 64;
#pragma unroll
    for (int j = 0; j < 64; ++j) acc[j] = fmaf(a, wr[j], acc[j]);
  }
  float hid[64];
#pragma unroll
  for (int j = 0; j < 64; ++j) hid[j] = fmaxf(acc[j], 0.f);

#pragma unroll
  for (int j = 0; j < 64; ++j) acc[j] = P.b1[j];
#pragma unroll
  for (int i = 0; i < 64; ++i) {
    const float a = hid[i];
    const float* wr = P.W1 + i * 64;
#pragma unroll
    for (int j = 0; j < 64; ++j) acc[j] = fmaf(a, wr[j], acc[j]);
  }
#pragma unroll
  for (int j = 0; j < 64; ++j) hid[j] = fmaxf(acc[j], 0.f);

  float so[33];
#pragma unroll
  for (int j = 0; j < 33; ++j) so[j] = P.bo[j];
#pragma unroll
  for (int i = 0; i < 64; ++i) {
    const float a = hid[i];
    const float* wr = P.Wo + i * 33;
#pragma unroll
    for (int j = 0; j < 33; ++j) so[j] = fmaf(a, wr[j], so[j]);
  }
  const float sdf = my_tanh(so[0]);
  float geo[32];
#pragma unroll
  for (int j = 0; j < 32; ++j) geo[j] = my_tanh(so[j + 1]);

#pragma unroll
  for (int j = 0; j < 64; ++j) acc[j] = P.bc0[j];
#pragma unroll
  for (int i = 0; i < 32; ++i) {
    const float a = geo[i];
    const float* wr = P.Wc0 + i * 64;
#pragma unroll
    for (int j = 0; j < 64; ++j) acc[j] = fmaf(a, wr[j], acc[j]);
  }
#pragma unroll
  for (int i = 0; i < 36; ++i) {
    const float a = feat[i];
    const float* wr = P.Wc0 + (32 + i) * 64;
#pragma unroll
    for (int j = 0; j < 64; ++j) acc[j] = fmaf(a, wr[j], acc[j]);
  }
#pragma unroll
  for (int j = 0; j < 64; ++j) hid[j] = fmaxf(acc[j], 0.f);

  float c1[32];
#pragma unroll
  for (int j = 0; j < 32; ++j) c1[j] = P.bc1[j];
#pragma unroll
  for (int i = 0; i < 64; ++i) {
    const float a = hid[i];
    const float* wr = P.Wc1 + i * 32;
#pragma unroll
    for (int j = 0; j < 32; ++j) c1[j] = fmaf(a, wr[j], c1[j]);
  }

  float r0 = P.bco[0], r1 = P.bco[1], r2 = P.bco[2];
#pragma unroll
  for (int i = 0; i < 32; ++i) {
    const float a = fmaxf(c1[i], 0.f);
    r0 = fmaf(a, P.Wco[i * 3 + 0], r0);
    r1 = fmaf(a, P.Wco[i * 3 + 1], r1);
    r2 = fmaf(a, P.Wco[i * 3 + 2], r2);
  }

  float4 o;
  o.x = my_sigmoid(r0);
  o.y = my_sigmoid(r1);
  o.z = my_sigmoid(r2);
  o.w = sdf;
  ((float4*)P.out)[tid] = o;
}

// ---------------- launch ----------------

extern "C" void kernel_launch(void* const* d_in, const int* in_sizes, int n_in,
                              void* d_out, int out_size, void* d_ws, size_t ws_size,
                              hipStream_t stream) {
  const int RES[4] = {128, 256, 512, 1024};
  const size_t planes_bytes = (size_t)4177920 * 8;
  const size_t hash_bytes = (size_t)16 * 65536 * 4;
  const size_t qs_bytes = (size_t)NPTS * 16;
  const size_t hist_bytes = (size_t)NBKT * 4;
  const size_t need_fused = planes_bytes + hash_bytes + qs_bytes + 2 * hist_bytes + 4096;
  const size_t need_mid = planes_bytes + 64;

  char* wsp = (char*)d_ws;
  const float* p = (const float*)d_in[0];

  if (ws_size >= need_fused) {
    size_t off = 0;
    PrepParams PP;
    PP.p = p;
    PP.hash = (const float*)d_in[13];
    const uint2* planes = (const uint2*)wsp;
    for (int i = 0; i < 12; ++i) {
      int R = RES[i / 3];
      PP.psrc[i] = (const float*)d_in[1 + i];
      PP.pdst[i] = (ushort4*)(wsp + off);
      off += (size_t)R * R * 8;
    }
    unsigned* hashb = (unsigned*)(wsp + off);
    PP.hashb = hashb;
    off += hash_bytes;
    float4* qs = (float4*)(wsp + off);
    off += qs_bytes;
    unsigned* hist = (unsigned*)(wsp + off);
    off += hist_bytes;
    unsigned* cursor = (unsigned*)(wsp + off);
    off += hist_bytes;
    unsigned* partial = (unsigned*)(wsp + off);
    off += 1024;
    unsigned* base = (unsigned*)(wsp + off);
    off += 1024;
    PP.hist = hist;

    hipMemsetAsync(hist, 0, hist_bytes, stream);
    prep_kernel<<<PB_PLANES + PB_HASH + PB_HIST, 256, 0, stream>>>(PP);
    scan1_kernel<<<256, 256, 0, stream>>>(hist, partial);
    scan2_kernel<<<1, 256, 0, stream>>>(partial, base);
    scan3_kernel<<<256, 256, 0, stream>>>(hist, base, cursor);
    scatter_kernel<<<NPTS / 256, 256, 0, stream>>>(p, cursor, qs);

    MlpWParams MP;
    MP.planes = planes;
    MP.hashb = hashb;
    MP.qs = qs;
    MP.W0 = (const float*)d_in[14]; MP.b0 = (const float*)d_in[15];
    MP.W1 = (const float*)d_in[16]; MP.b1 = (const float*)d_in[17];
    MP.Wo = (const float*)d_in[18]; MP.bo = (const float*)d_in[19];
    MP.Wc0 = (const float*)d_in[20]; MP.bc0 = (const float*)d_in[21];
    MP.Wc1 = (const float*)d_in[22]; MP.bc1 = (const float*)d_in[23];
    MP.Wco = (const float*)d_in[24]; MP.bco = (const float*)d_in[25];
    MP.out = (float*)d_out;
    mlp_fused<<<512, MLP_THREADS, 0, stream>>>(MP);
    return;
  }

  DecParams P;
  P.p = p;
  for (int i = 0; i < 12; ++i) P.pl[i] = (const float*)d_in[1 + i];
  P.hash = (const float*)d_in[13];
  P.W0  = (const float*)d_in[14]; P.b0  = (const float*)d_in[15];
  P.W1  = (const float*)d_in[16]; P.b1  = (const float*)d_in[17];
  P.Wo  = (const float*)d_in[18]; P.bo  = (const float*)d_in[19];
  P.Wc0 = (const float*)d_in[20]; P.bc0 = (const float*)d_in[21];
  P.Wc1 = (const float*)d_in[22]; P.bc1 = (const float*)d_in[23];
  P.Wco = (const float*)d_in[24]; P.bco = (const float*)d_in[25];
  P.out = (float*)d_out;

  if (ws_size >= need_mid) {
    size_t off = 0;
    for (int i = 0; i < 12; ++i) {
      int R = RES[i / 3];
      int n = R * R;
      P.pli[i] = (const uint2*)(wsp + off);
      repack_plane<<<(n + 255) / 256, 256, 0, stream>>>(
          (const float*)d_in[1 + i], (ushort4*)(wsp + off), R);
      off += (size_t)n * 8;
    }
    dec_kernel<true><<<NPTS / 256, 256, 0, stream>>>(P);
  } else {
    for (int i = 0; i < 12; ++i) P.pli[i] = nullptr;
    dec_kernel<false><<<NPTS / 256, 256, 0, stream>>>(P);
  }
}